// Round 1
// baseline (419.622 us; speedup 1.0000x reference)
//
#include <hip/hip_runtime.h>
#include <math.h>

namespace {

constexpr int Bn   = 4;
constexpr int Nn   = 2048;
constexpr int Kn   = 32;
constexpr int CIN  = 64;
constexpr int COUT = 64;
constexpr int Mn   = 8;
constexpr int HIDn = 16;
constexpr int NK   = Nn * Kn;       // 65536
constexpr int PTOT = Bn * NK;       // 262144
constexpr float EPSf = 1e-5f;

// ws float-offset layout
constexpr int WS_SUM1 = 0;    // 16 floats
constexpr int WS_SQ1  = 16;   // 16
constexpr int WS_SC1  = 32;   // 16
constexpr int WS_SH1  = 48;   // 16
constexpr int WS_SUM2 = 64;   // 64
constexpr int WS_SQ2  = 128;  // 64
constexpr int WS_SC2  = 192;  // 64
constexpr int WS_SH2  = 256;  // 64
constexpr int WS_TOT  = 320;

// Build 14-ch geometric feature and h = w1 @ x  (16 channels) for one position.
__device__ __forceinline__ void geom_h(
    const float* __restrict__ xyz, const float* __restrict__ dist,
    const float* __restrict__ nrm, const float* __restrict__ ang,
    const float* __restrict__ w1, int b, int rem, float h[HIDn]) {
  const int cbase = rem & ~(Kn - 1);   // k = 0 element of this (b, n)
  float x[14];
  const float invd = 1.0f / (1.0f + dist[b * NK + rem]);
  float xe = 0.f, ne = 0.f;
#pragma unroll
  for (int d = 0; d < 3; ++d) {
    const int base = (b * 3 + d) * NK;
    const float gx = xyz[base + rem];
    const float gn = nrm[base + rem];
    const float cn = nrm[base + cbase];
    const float ga = ang[base + rem];
    const float nd = gn - cn;
    x[d] = gx; x[4 + d] = gn; x[7 + d] = nd; x[11 + d] = ga;
    xe += gx * gx; ne += nd * nd;
  }
  x[3]  = sqrtf(xe);
  x[10] = sqrtf(ne);
#pragma unroll
  for (int i = 0; i < 14; ++i) x[i] *= invd;
#pragma unroll
  for (int o = 0; o < HIDn; ++o) {
    float s = 0.f;
#pragma unroll
    for (int c = 0; c < 14; ++c) s = fmaf(w1[o * 14 + c], x[c], s);
    h[o] = s;
  }
}

__global__ __launch_bounds__(512) void k0_zero(float* __restrict__ ws) {
  const int t = threadIdx.x;
  if (t < WS_TOT) ws[t] = 0.f;
}

// Pass 1: BN1 statistics over h (16 channels, count = PTOT)
__global__ __launch_bounds__(256) void k1_stats1(
    const float* __restrict__ xyz, const float* __restrict__ dist,
    const float* __restrict__ nrm, const float* __restrict__ ang,
    const float* __restrict__ w1, float* __restrict__ ws) {
  const int pos = blockIdx.x * 256 + threadIdx.x;
  const int b   = pos >> 16;
  const int rem = pos & (NK - 1);
  float h[HIDn];
  geom_h(xyz, dist, nrm, ang, w1, b, rem, h);

  float v[32];
#pragma unroll
  for (int i = 0; i < 16; ++i) { v[i] = h[i]; v[16 + i] = h[i] * h[i]; }
#pragma unroll
  for (int off = 32; off >= 1; off >>= 1) {
#pragma unroll
    for (int i = 0; i < 32; ++i) v[i] += __shfl_xor(v[i], off);
  }
  // after butterfly every lane holds all 32 wave-totals; route value i to lane i
  const int lane = threadIdx.x & 63;
  const int wid  = threadIdx.x >> 6;
  float mv = 0.f;
#pragma unroll
  for (int i = 0; i < 32; ++i) { if (lane == i) mv = v[i]; }
  __shared__ float red[4][32];
  if (lane < 32) red[wid][lane] = mv;
  __syncthreads();
  if (threadIdx.x < 32) {
    const float tot = red[0][threadIdx.x] + red[1][threadIdx.x] +
                      red[2][threadIdx.x] + red[3][threadIdx.x];
    atomicAdd(&ws[WS_SUM1 + threadIdx.x], tot);  // [0:16]=sum, [16:32]=sumsq
  }
}

__global__ __launch_bounds__(64) void k2_fin1(const float* __restrict__ g1,
                                              const float* __restrict__ b1,
                                              float* __restrict__ ws) {
  const int c = threadIdx.x;
  if (c >= HIDn) return;
  const float inv  = 1.0f / (float)PTOT;
  const float mean = ws[WS_SUM1 + c] * inv;
  const float var  = ws[WS_SQ1 + c] * inv - mean * mean;
  const float sc   = g1[c] * rsqrtf(var + EPSf);
  ws[WS_SC1 + c] = sc;
  ws[WS_SH1 + c] = b1[c] - mean * sc;
}

// Pass 2: scores + weight-bank contraction -> out_pre (to d_out) + BN2 sums
__global__ __launch_bounds__(256) void k3_main(
    const float* __restrict__ xyz, const float* __restrict__ dist,
    const float* __restrict__ nrm, const float* __restrict__ ang,
    const float* __restrict__ feature, const float* __restrict__ w1,
    const float* __restrict__ w2, const float* __restrict__ bias2,
    const float* __restrict__ wb, float* __restrict__ ws,
    float* __restrict__ out) {
  const int pos = blockIdx.x * 256 + threadIdx.x;
  const int b   = pos >> 16;
  const int rem = pos & (NK - 1);

  float h[HIDn];
  geom_h(xyz, dist, nrm, ang, w1, b, rem, h);
#pragma unroll
  for (int o = 0; o < HIDn; ++o)
    h[o] = fmaxf(fmaf(h[o], ws[WS_SC1 + o], ws[WS_SH1 + o]), 0.f);

  float s[Mn];
#pragma unroll
  for (int m = 0; m < Mn; ++m) {
    float a = bias2[m];
#pragma unroll
    for (int j = 0; j < HIDn; ++j) a = fmaf(w2[m * HIDn + j], h[j], a);
    s[m] = a;
  }
  float mx = s[0];
#pragma unroll
  for (int m = 1; m < Mn; ++m) mx = fmaxf(mx, s[m]);
  float sc[Mn];
  float sum = 0.f;
#pragma unroll
  for (int m = 0; m < Mn; ++m) { sc[m] = expf(s[m] - mx); sum += sc[m]; }
  const float inv = 1.0f / (sum + expf(-mx));   // softmax_one denominator
#pragma unroll
  for (int m = 0; m < Mn; ++m) sc[m] *= inv;

  float feat[CIN];
#pragma unroll
  for (int c = 0; c < CIN; ++c) feat[c] = feature[(b * CIN + c) * NK + rem];

  float acc[COUT];
#pragma unroll
  for (int o = 0; o < COUT; ++o) acc[o] = 0.f;

  // out[o] = sum_c sum_m (feat[c]*sc[m]) * Wb[c, m*64+o]
  // Wb indices are loop-uniform -> scalar loads; inner loop is pure v_fmac.
  for (int c = 0; c < CIN; ++c) {
    const float f = feat[c];
    const float4* __restrict__ w4 =
        reinterpret_cast<const float4*>(wb + c * (Mn * COUT));
#pragma unroll
    for (int m = 0; m < Mn; ++m) {
      const float p = f * sc[m];
#pragma unroll
      for (int o4 = 0; o4 < COUT / 4; ++o4) {
        const float4 w = w4[m * (COUT / 4) + o4];
        acc[o4 * 4 + 0] = fmaf(p, w.x, acc[o4 * 4 + 0]);
        acc[o4 * 4 + 1] = fmaf(p, w.y, acc[o4 * 4 + 1]);
        acc[o4 * 4 + 2] = fmaf(p, w.z, acc[o4 * 4 + 2]);
        acc[o4 * 4 + 3] = fmaf(p, w.w, acc[o4 * 4 + 3]);
      }
    }
  }

#pragma unroll
  for (int o = 0; o < COUT; ++o) out[(b * COUT + o) * NK + rem] = acc[o];

  // BN2 stats: reuse feat[] for squares, butterfly both, route to lanes.
#pragma unroll
  for (int o = 0; o < COUT; ++o) feat[o] = acc[o] * acc[o];
#pragma unroll
  for (int off = 32; off >= 1; off >>= 1) {
#pragma unroll
    for (int o = 0; o < COUT; ++o) {
      acc[o]  += __shfl_xor(acc[o], off);
      feat[o] += __shfl_xor(feat[o], off);
    }
  }
  const int lane = threadIdx.x & 63;
  const int wid  = threadIdx.x >> 6;
  float mysum = 0.f, mysq = 0.f;
#pragma unroll
  for (int o = 0; o < COUT; ++o) {
    if (lane == o) { mysum = acc[o]; mysq = feat[o]; }
  }
  __shared__ float red[4][128];
  red[wid][lane]      = mysum;
  red[wid][64 + lane] = mysq;
  __syncthreads();
  if (threadIdx.x < 128) {
    const float tot = red[0][threadIdx.x] + red[1][threadIdx.x] +
                      red[2][threadIdx.x] + red[3][threadIdx.x];
    atomicAdd(&ws[WS_SUM2 + threadIdx.x], tot);  // [64:128]=sum2, [128:192]=sq2
  }
}

__global__ __launch_bounds__(64) void k4_fin2(const float* __restrict__ gamma,
                                              const float* __restrict__ beta,
                                              float* __restrict__ ws) {
  const int c = threadIdx.x;
  const float inv  = 1.0f / (float)PTOT;
  const float mean = ws[WS_SUM2 + c] * inv;
  const float var  = ws[WS_SQ2 + c] * inv - mean * mean;
  const float sc   = gamma[c] * rsqrtf(var + EPSf);
  ws[WS_SC2 + c] = sc;
  ws[WS_SH2 + c] = beta[c] - mean * sc;
}

// Pass 3: apply BN2 + ReLU in place (float4)
__global__ __launch_bounds__(256) void k5_bn2(float* __restrict__ out,
                                              const float* __restrict__ ws) {
  const int i4 = blockIdx.x * 256 + threadIdx.x;   // over PTOT*COUT/4 float4
  const int o  = (i4 >> 14) & 63;                  // (i4*4 >> 16) & 63
  const float sc = ws[WS_SC2 + o];
  const float sh = ws[WS_SH2 + o];
  float4 v = reinterpret_cast<float4*>(out)[i4];
  v.x = fmaxf(fmaf(v.x, sc, sh), 0.f);
  v.y = fmaxf(fmaf(v.y, sc, sh), 0.f);
  v.z = fmaxf(fmaf(v.z, sc, sh), 0.f);
  v.w = fmaxf(fmaf(v.w, sc, sh), 0.f);
  reinterpret_cast<float4*>(out)[i4] = v;
}

}  // namespace

extern "C" void kernel_launch(void* const* d_in, const int* in_sizes, int n_in,
                              void* d_out, int out_size, void* d_ws, size_t ws_size,
                              hipStream_t stream) {
  const float* xyz     = (const float*)d_in[0];
  const float* dist    = (const float*)d_in[1];
  const float* nrm     = (const float*)d_in[2];
  const float* ang     = (const float*)d_in[3];
  const float* feature = (const float*)d_in[4];
  const float* w1      = (const float*)d_in[5];
  const float* g1      = (const float*)d_in[6];
  const float* b1      = (const float*)d_in[7];
  const float* w2      = (const float*)d_in[8];
  const float* bias2   = (const float*)d_in[9];
  const float* wb      = (const float*)d_in[10];
  const float* gamma   = (const float*)d_in[11];
  const float* beta    = (const float*)d_in[12];
  float* out = (float*)d_out;
  float* ws  = (float*)d_ws;

  hipLaunchKernelGGL(k0_zero, dim3(1), dim3(512), 0, stream, ws);
  hipLaunchKernelGGL(k1_stats1, dim3(PTOT / 256), dim3(256), 0, stream,
                     xyz, dist, nrm, ang, w1, ws);
  hipLaunchKernelGGL(k2_fin1, dim3(1), dim3(64), 0, stream, g1, b1, ws);
  hipLaunchKernelGGL(k3_main, dim3(PTOT / 256), dim3(256), 0, stream,
                     xyz, dist, nrm, ang, feature, w1, w2, bias2, wb, ws, out);
  hipLaunchKernelGGL(k4_fin2, dim3(1), dim3(64), 0, stream, gamma, beta, ws);
  hipLaunchKernelGGL(k5_bn2, dim3((PTOT * COUT / 4) / 256), dim3(256), 0, stream,
                     out, ws);
}

// Round 2
// 98.682 us; speedup vs baseline: 4.2523x; 4.2523x over previous
//
#include <hip/hip_runtime.h>
#include <hip/hip_bf16.h>
#include <math.h>

namespace {

constexpr int Kn   = 32;
constexpr int CIN  = 64;
constexpr int COUT = 64;
constexpr int Mn   = 8;
constexpr int HIDn = 16;
constexpr int NK   = 65536;         // N*K
constexpr int PTOT = 262144;        // B*N*K
constexpr float EPSf = 1e-5f;

// ws float-offset layout
constexpr int WS_SUM1 = 0;    // 16 floats
constexpr int WS_SQ1  = 16;   // 16
constexpr int WS_SC1  = 32;   // 16
constexpr int WS_SH1  = 48;   // 16
constexpr int WS_SUM2 = 64;   // 64
constexpr int WS_SQ2  = 128;  // 64
constexpr int WS_SC2  = 192;  // 64
constexpr int WS_SH2  = 256;  // 64
constexpr int WS_TOT  = 320;

typedef short bf16x8 __attribute__((ext_vector_type(8)));
typedef float f32x4  __attribute__((ext_vector_type(4)));

__device__ __forceinline__ short f2bf(float f) {
  union { __hip_bfloat16 h; unsigned short u; } cv;
  cv.h = __float2bfloat16(f);
  return (short)cv.u;
}

// Build 14-ch geometric feature and h = w1 @ x (16 channels) for one position.
__device__ __forceinline__ void geom_h(
    const float* __restrict__ xyz, const float* __restrict__ dist,
    const float* __restrict__ nrm, const float* __restrict__ ang,
    const float* __restrict__ w1, int b, int rem, float h[HIDn]) {
  const int cbase = rem & ~(Kn - 1);   // k = 0 element of this (b, n)
  float x[14];
  const float invd = 1.0f / (1.0f + dist[b * NK + rem]);
  float xe = 0.f, ne = 0.f;
#pragma unroll
  for (int d = 0; d < 3; ++d) {
    const int base = (b * 3 + d) * NK;
    const float gx = xyz[base + rem];
    const float gn = nrm[base + rem];
    const float cn = nrm[base + cbase];
    const float ga = ang[base + rem];
    const float nd = gn - cn;
    x[d] = gx; x[4 + d] = gn; x[7 + d] = nd; x[11 + d] = ga;
    xe += gx * gx; ne += nd * nd;
  }
  x[3]  = sqrtf(xe);
  x[10] = sqrtf(ne);
#pragma unroll
  for (int i = 0; i < 14; ++i) x[i] *= invd;
#pragma unroll
  for (int o = 0; o < HIDn; ++o) {
    float s = 0.f;
#pragma unroll
    for (int c = 0; c < 14; ++c) s = fmaf(w1[o * 14 + c], x[c], s);
    h[o] = s;
  }
}

__global__ __launch_bounds__(512) void k0_zero(float* __restrict__ ws) {
  const int t = threadIdx.x;
  if (t < WS_TOT) ws[t] = 0.f;
}

// Pass 1: BN1 statistics over h (16 channels, count = PTOT)
__global__ __launch_bounds__(256) void k1_stats1(
    const float* __restrict__ xyz, const float* __restrict__ dist,
    const float* __restrict__ nrm, const float* __restrict__ ang,
    const float* __restrict__ w1, float* __restrict__ ws) {
  const int pos = blockIdx.x * 256 + threadIdx.x;
  const int b   = pos >> 16;
  const int rem = pos & (NK - 1);
  float h[HIDn];
  geom_h(xyz, dist, nrm, ang, w1, b, rem, h);

  float v[32];
#pragma unroll
  for (int i = 0; i < 16; ++i) { v[i] = h[i]; v[16 + i] = h[i] * h[i]; }
#pragma unroll
  for (int off = 32; off >= 1; off >>= 1) {
#pragma unroll
    for (int i = 0; i < 32; ++i) v[i] += __shfl_xor(v[i], off);
  }
  const int lane = threadIdx.x & 63;
  const int wid  = threadIdx.x >> 6;
  float mv = 0.f;
#pragma unroll
  for (int i = 0; i < 32; ++i) { if (lane == i) mv = v[i]; }
  __shared__ float red[4][32];
  if (lane < 32) red[wid][lane] = mv;
  __syncthreads();
  if (threadIdx.x < 32) {
    const float tot = red[0][threadIdx.x] + red[1][threadIdx.x] +
                      red[2][threadIdx.x] + red[3][threadIdx.x];
    atomicAdd(&ws[WS_SUM1 + threadIdx.x], tot);  // [0:16]=sum, [16:32]=sumsq
  }
}

__global__ __launch_bounds__(64) void k2_fin1(const float* __restrict__ g1,
                                              const float* __restrict__ b1,
                                              float* __restrict__ ws) {
  const int c = threadIdx.x;
  if (c >= HIDn) return;
  const float inv  = 1.0f / (float)PTOT;
  const float mean = ws[WS_SUM1 + c] * inv;
  const float var  = ws[WS_SQ1 + c] * inv - mean * mean;
  const float sc   = g1[c] * rsqrtf(var + EPSf);
  ws[WS_SC1 + c] = sc;
  ws[WS_SH1 + c] = b1[c] - mean * sc;
}

// Pass 2 (MFMA): scores + weight-bank GEMM -> out_pre (d_out) + BN2 sums.
// GEMM: out[p,o] = sum_k A[p,k]*Wb[k,o], k=(c,m)=c*8+m, K=512.
// A[p,c*8+m] = feat[p,c]*sc[p,m] generated in registers.
// Per wave: 2 row-tiles (32 positions) x 4 col-tiles (64 outputs).
__global__ __launch_bounds__(512, 4) void k3_mfma(
    const float* __restrict__ xyz, const float* __restrict__ dist,
    const float* __restrict__ nrm, const float* __restrict__ ang,
    const float* __restrict__ feature, const float* __restrict__ w1,
    const float* __restrict__ w2, const float* __restrict__ bias2,
    const float* __restrict__ wb, float* __restrict__ ws,
    float* __restrict__ out) {
  __shared__ short lds_b[16 * 4 * 64 * 8];   // 64 KB: [t][colt][lane][8] bf16
  __shared__ float red[8][128];

  const int tid = threadIdx.x;
  const int l   = tid & 63;
  const int w   = tid >> 6;          // wave 0..7
  const int g   = l >> 4;            // k-lane-group 0..3
  const int row = l & 15;            // A row within tile / D col index

  // ---- stage Wb into LDS as fragment-major bf16 ----
  // fragment fi = t*4+colt; lane l element j = Wb[k = (t*4+g)*8 + j][colt*16+row]
#pragma unroll
  for (int ff = 0; ff < 8; ++ff) {
    const int fi   = w * 8 + ff;
    const int t    = fi >> 2;
    const int colt = fi & 3;
    const int c    = t * 4 + g;
    const int o    = colt * 16 + row;
    bf16x8 frag;
#pragma unroll
    for (int j = 0; j < 8; ++j) frag[j] = f2bf(wb[c * 512 + j * 64 + o]);
    *reinterpret_cast<bf16x8*>(&lds_b[(fi * 64 + l) * 8]) = frag;
  }

  // ---- scorenet: lane computes position pos0 + (l&31); 1x work per wave ----
  const int pos0 = blockIdx.x * 256 + w * 32;   // wave's first position
  const int myp  = pos0 + (l & 31);
  const int b    = myp >> 16;
  const int rem  = myp & (NK - 1);
  float h[HIDn];
  geom_h(xyz, dist, nrm, ang, w1, b, rem, h);
#pragma unroll
  for (int o = 0; o < HIDn; ++o)
    h[o] = fmaxf(fmaf(h[o], ws[WS_SC1 + o], ws[WS_SH1 + o]), 0.f);
  float s[Mn];
#pragma unroll
  for (int m = 0; m < Mn; ++m) {
    float a = bias2[m];
#pragma unroll
    for (int j = 0; j < HIDn; ++j) a = fmaf(w2[m * HIDn + j], h[j], a);
    s[m] = a;
  }
  float mx = s[0];
#pragma unroll
  for (int m = 1; m < Mn; ++m) mx = fmaxf(mx, s[m]);
  float sc[Mn];
  float ssum = 0.f;
#pragma unroll
  for (int m = 0; m < Mn; ++m) { sc[m] = expf(s[m] - mx); ssum += sc[m]; }
  const float inv = 1.0f / (ssum + expf(-mx));
#pragma unroll
  for (int m = 0; m < Mn; ++m) sc[m] *= inv;

  // broadcast scores to the lanes that own each row
  float scA[Mn], scB[Mn];
#pragma unroll
  for (int m = 0; m < Mn; ++m) {
    scA[m] = __shfl(sc[m], row);        // tile 0 rows: lanes 0..15
    scB[m] = __shfl(sc[m], row + 16);   // tile 1 rows: lanes 16..31
  }

  __syncthreads();

  // ---- K loop: 16 steps of K=32 ----
  const int bb      = pos0 >> 16;
  const int wav_rem = pos0 & (NK - 1);
  const float* fbase = feature + (size_t)bb * CIN * NK + wav_rem;
  f32x4 acc[2][4];
#pragma unroll
  for (int i = 0; i < 2; ++i)
#pragma unroll
    for (int j = 0; j < 4; ++j) acc[i][j] = (f32x4){0.f, 0.f, 0.f, 0.f};

#pragma unroll
  for (int t = 0; t < 16; ++t) {
    const int c = t * 4 + g;
    const float fA = fbase[c * NK + row];
    const float fB = fbase[c * NK + 16 + row];
    bf16x8 a0, a1;
#pragma unroll
    for (int m = 0; m < Mn; ++m) {
      a0[m] = f2bf(fA * scA[m]);
      a1[m] = f2bf(fB * scB[m]);
    }
#pragma unroll
    for (int ct = 0; ct < 4; ++ct) {
      const bf16x8 bfr =
          *reinterpret_cast<const bf16x8*>(&lds_b[((t * 4 + ct) * 64 + l) * 8]);
      acc[0][ct] = __builtin_amdgcn_mfma_f32_16x16x32_bf16(a0, bfr, acc[0][ct], 0, 0, 0);
      acc[1][ct] = __builtin_amdgcn_mfma_f32_16x16x32_bf16(a1, bfr, acc[1][ct], 0, 0, 0);
    }
  }

  // ---- store: D reg i = row (lane>>4)*4+i, col = lane&15 (m89-verified) ----
  // 4 regs = 4 consecutive positions -> float4 store per (tile, coltile).
  float* obase = out + (size_t)bb * COUT * NK + wav_rem;
#pragma unroll
  for (int tau = 0; tau < 2; ++tau) {
#pragma unroll
    for (int ct = 0; ct < 4; ++ct) {
      const int o = ct * 16 + row;
      *reinterpret_cast<f32x4*>(&obase[(size_t)o * NK + tau * 16 + 4 * g]) =
          acc[tau][ct];
    }
  }

  // ---- BN2 partial sums ----
  float s2[4], q2[4];
#pragma unroll
  for (int ct = 0; ct < 4; ++ct) {
    float a = 0.f, q = 0.f;
#pragma unroll
    for (int tau = 0; tau < 2; ++tau)
#pragma unroll
      for (int i = 0; i < 4; ++i) {
        const float v = acc[tau][ct][i];
        a += v; q += v * v;
      }
    s2[ct] = a; q2[ct] = q;
  }
#pragma unroll
  for (int ct = 0; ct < 4; ++ct) {
    s2[ct] += __shfl_xor(s2[ct], 16); s2[ct] += __shfl_xor(s2[ct], 32);
    q2[ct] += __shfl_xor(q2[ct], 16); q2[ct] += __shfl_xor(q2[ct], 32);
  }
  if (l < 16) {
#pragma unroll
    for (int ct = 0; ct < 4; ++ct) {
      red[w][ct * 16 + l]      = s2[ct];
      red[w][64 + ct * 16 + l] = q2[ct];
    }
  }
  __syncthreads();
  if (tid < 128) {
    float tot = 0.f;
#pragma unroll
    for (int ww = 0; ww < 8; ++ww) tot += red[ww][tid];
    atomicAdd(&ws[WS_SUM2 + tid], tot);   // [64:128]=sum2, [128:192]=sq2
  }
}

__global__ __launch_bounds__(64) void k4_fin2(const float* __restrict__ gamma,
                                              const float* __restrict__ beta,
                                              float* __restrict__ ws) {
  const int c = threadIdx.x;
  const float inv  = 1.0f / (float)PTOT;
  const float mean = ws[WS_SUM2 + c] * inv;
  const float var  = ws[WS_SQ2 + c] * inv - mean * mean;
  const float sc   = gamma[c] * rsqrtf(var + EPSf);
  ws[WS_SC2 + c] = sc;
  ws[WS_SH2 + c] = beta[c] - mean * sc;
}

// Pass 3: apply BN2 + ReLU in place (float4)
__global__ __launch_bounds__(256) void k5_bn2(float* __restrict__ out,
                                              const float* __restrict__ ws) {
  const int i4 = blockIdx.x * 256 + threadIdx.x;   // over PTOT*COUT/4 float4
  const int o  = (i4 >> 14) & 63;
  const float sc = ws[WS_SC2 + o];
  const float sh = ws[WS_SH2 + o];
  float4 v = reinterpret_cast<float4*>(out)[i4];
  v.x = fmaxf(fmaf(v.x, sc, sh), 0.f);
  v.y = fmaxf(fmaf(v.y, sc, sh), 0.f);
  v.z = fmaxf(fmaf(v.z, sc, sh), 0.f);
  v.w = fmaxf(fmaf(v.w, sc, sh), 0.f);
  reinterpret_cast<float4*>(out)[i4] = v;
}

}  // namespace

extern "C" void kernel_launch(void* const* d_in, const int* in_sizes, int n_in,
                              void* d_out, int out_size, void* d_ws, size_t ws_size,
                              hipStream_t stream) {
  const float* xyz     = (const float*)d_in[0];
  const float* dist    = (const float*)d_in[1];
  const float* nrm     = (const float*)d_in[2];
  const float* ang     = (const float*)d_in[3];
  const float* feature = (const float*)d_in[4];
  const float* w1      = (const float*)d_in[5];
  const float* g1      = (const float*)d_in[6];
  const float* b1      = (const float*)d_in[7];
  const float* w2      = (const float*)d_in[8];
  const float* bias2   = (const float*)d_in[9];
  const float* wb      = (const float*)d_in[10];
  const float* gamma   = (const float*)d_in[11];
  const float* beta    = (const float*)d_in[12];
  float* out = (float*)d_out;
  float* ws  = (float*)d_ws;

  hipLaunchKernelGGL(k0_zero, dim3(1), dim3(512), 0, stream, ws);
  hipLaunchKernelGGL(k1_stats1, dim3(PTOT / 256), dim3(256), 0, stream,
                     xyz, dist, nrm, ang, w1, ws);
  hipLaunchKernelGGL(k2_fin1, dim3(1), dim3(64), 0, stream, g1, b1, ws);
  hipLaunchKernelGGL(k3_mfma, dim3(PTOT / 256), dim3(512), 0, stream,
                     xyz, dist, nrm, ang, feature, w1, w2, bias2, wb, ws, out);
  hipLaunchKernelGGL(k4_fin2, dim3(1), dim3(64), 0, stream, gamma, beta, ws);
  hipLaunchKernelGGL(k5_bn2, dim3((PTOT * COUT / 4) / 256), dim3(256), 0, stream,
                     out, ws);
}